// Round 1
// baseline (718.948 us; speedup 1.0000x reference)
//
#include <hip/hip_runtime.h>
#include <hip/hip_bf16.h>
#include <math.h>

// B=64, N=512, D=1024, SHELL=64, RFF=32, ORDER=4, COMBINED=64
// Pipeline: x->bf16; SC=x@[Wsh;Wch]^T; features->tp; phi=tp@Wcomb^T;
// logits=phi@phi^T (batched); softmax(T,causal)->attn(bf16);
// Vt = (x@Wv^T+bv)^T (bf16, transposed epilogue); out2=attn@Vt^T; out=out2@Wo^T+bo.

using u16 = unsigned short;
typedef short short8 __attribute__((ext_vector_type(8)));   // 8 x bf16 (4 VGPR) per guide §3
typedef float f32x4 __attribute__((ext_vector_type(4)));

__device__ __forceinline__ u16 f2bf(float f) {
  unsigned u = __float_as_uint(f);
  return (u16)((u + 0x7fffu + ((u >> 16) & 1u)) >> 16);   // RNE
}

// ---------------- x -> bf16 ----------------
__global__ __launch_bounds__(256) void convert_x_kernel(const float* __restrict__ in,
                                                        u16* __restrict__ out, int n4) {
  int idx = blockIdx.x * 256 + threadIdx.x;
  int stride = gridDim.x * 256;
  for (int i = idx; i < n4; i += stride) {
    float4 v = reinterpret_cast<const float4*>(in)[i];
    ushort4 o;
    o.x = f2bf(v.x); o.y = f2bf(v.y); o.z = f2bf(v.z); o.w = f2bf(v.w);
    reinterpret_cast<ushort4*>(out)[i] = o;
  }
}

// ---------------- weights -> bf16 (Wv, Wo, Wcat=[Wsh;Wch;0], Wcomb padded to 128 rows) ----
__global__ __launch_bounds__(256) void prep_weights_kernel(
    const float* __restrict__ Wv, const float* __restrict__ Wo,
    const float* __restrict__ Wsh, const float* __restrict__ Wch,
    const float* __restrict__ Wcb,
    u16* __restrict__ wvb, u16* __restrict__ wob,
    u16* __restrict__ wcat, u16* __restrict__ wcbb) {
  int i = blockIdx.x * 256 + threadIdx.x;
  if (i < 1048576) { wvb[i] = f2bf(Wv[i]); return; }
  i -= 1048576;
  if (i < 1048576) { wob[i] = f2bf(Wo[i]); return; }
  i -= 1048576;
  if (i < 131072) {  // Wcat: 128 rows x 1024 (rows 0-63 Wsh, row 64 Wch, rest 0)
    int row = i >> 10, e = i & 1023;
    float v = (row < 64) ? Wsh[i] : ((row == 64) ? Wch[e] : 0.0f);
    wcat[i] = f2bf(v);
    return;
  }
  i -= 131072;
  if (i < 40960) {   // Wcomb padded: 128 rows x 320
    int row = i / 320;
    wcbb[i] = f2bf(row < 64 ? Wcb[i] : 0.0f);
  }
}

// ---------------- generic bf16 MFMA GEMM: C = A @ Bt^T (+bias[n]) --------------
// A: M x K (lda), Bt: N x K (ldb), both row-major K-contiguous, all mult-of-tile.
// OUT_MODE: 0 = fp32 C[m*ldc+n], 1 = bf16 C[m*ldc+n], 2 = bf16 transposed C[n*ldc+m].
template<int OUT_MODE>
__global__ __launch_bounds__(256) void gemm_bt(
    const u16* __restrict__ A, const u16* __restrict__ Bt,
    const float* __restrict__ bias, void* __restrict__ Cv,
    int M, int N, int K, int lda, int ldb, int ldc,
    long long sA, long long sB, long long sC) {
  (void)M; (void)N;
  __shared__ u16 lA[128 * 32];
  __shared__ u16 lB[128 * 32];
  const int t = threadIdx.x;
  const int lane = t & 63;
  const int w = t >> 6;
  const u16* Ag = A + (size_t)blockIdx.z * sA;
  const u16* Bg = Bt + (size_t)blockIdx.z * sB;
  const int m0 = blockIdx.y * 128;
  const int n0 = blockIdx.x * 128;
  const int wm = (w >> 1) * 64;   // 2x2 waves, 64x64 each
  const int wn = (w & 1) * 64;
  const int rl = lane & 15;
  const int kl = (lane >> 4) * 8;
  const int r0 = t >> 2;          // staging row (0..63)
  const int c0 = (t & 3) * 8;     // staging col

  f32x4 acc[4][4] = {};

  for (int k0 = 0; k0 < K; k0 += 32) {
    #pragma unroll
    for (int ch = 0; ch < 2; ++ch) {
      const int row = ch * 64 + r0;
      short8 va = *reinterpret_cast<const short8*>(Ag + (size_t)(m0 + row) * lda + k0 + c0);
      short8 vb = *reinterpret_cast<const short8*>(Bg + (size_t)(n0 + row) * ldb + k0 + c0);
      *reinterpret_cast<short8*>(&lA[row * 32 + c0]) = va;
      *reinterpret_cast<short8*>(&lB[row * 32 + c0]) = vb;
    }
    __syncthreads();
    short8 af[4], bfr[4];
    #pragma unroll
    for (int mi = 0; mi < 4; ++mi)
      af[mi] = *reinterpret_cast<const short8*>(&lA[(wm + mi * 16 + rl) * 32 + kl]);
    #pragma unroll
    for (int ni = 0; ni < 4; ++ni)
      bfr[ni] = *reinterpret_cast<const short8*>(&lB[(wn + ni * 16 + rl) * 32 + kl]);
    #pragma unroll
    for (int mi = 0; mi < 4; ++mi) {
      #pragma unroll
      for (int ni = 0; ni < 4; ++ni)
        acc[mi][ni] = __builtin_amdgcn_mfma_f32_16x16x32_bf16(af[mi], bfr[ni], acc[mi][ni], 0, 0, 0);
    }
    __syncthreads();
  }

  // C/D layout: col = lane&15, row = (lane>>4)*4 + reg  [guide §3, m89/m91 verified]
  const int cm = (lane >> 4) * 4;
  #pragma unroll
  for (int mi = 0; mi < 4; ++mi) {
    #pragma unroll
    for (int ni = 0; ni < 4; ++ni) {
      const int gm = m0 + wm + mi * 16 + cm;
      const int gn = n0 + wn + ni * 16 + rl;
      const float bsv = bias ? bias[gn] : 0.0f;
      if (OUT_MODE == 0) {
        float* C = (float*)Cv + (size_t)blockIdx.z * sC;
        #pragma unroll
        for (int r = 0; r < 4; ++r)
          C[(size_t)(gm + r) * ldc + gn] = acc[mi][ni][r] + bsv;
      } else if (OUT_MODE == 1) {
        u16* C = (u16*)Cv + (size_t)blockIdx.z * sC;
        #pragma unroll
        for (int r = 0; r < 4; ++r)
          C[(size_t)(gm + r) * ldc + gn] = f2bf(acc[mi][ni][r] + bsv);
      } else {
        u16* C = (u16*)Cv + (size_t)blockIdx.z * sC;
        ushort4 pk;
        pk.x = f2bf(acc[mi][ni][0] + bsv);
        pk.y = f2bf(acc[mi][ni][1] + bsv);
        pk.z = f2bf(acc[mi][ni][2] + bsv);
        pk.w = f2bf(acc[mi][ni][3] + bsv);
        *reinterpret_cast<ushort4*>(&C[(size_t)gn * ldc + gm]) = pk;
      }
    }
  }
}

// ---------------- features: SC(fp32 32768x128) -> tp(bf16 32768x320) ----------------
// wave per row: lane = shell dim; tp[row][m*64+s] = phi_c[m]*phi_s[s]
__global__ __launch_bounds__(256) void features_kernel(
    const float* __restrict__ SC, const float* __restrict__ b_shell,
    const float* __restrict__ b_charge, const float* __restrict__ omega,
    const float* __restrict__ rff_bias, u16* __restrict__ tp) {
  __shared__ __align__(16) float sm[4][64];
  const int lane = threadIdx.x & 63;
  const int w = threadIdx.x >> 6;
  const int row = blockIdx.x * 4 + w;
  const float* sc = SC + (size_t)row * 128;
  float s = sc[lane] + b_shell[lane];
  float ss = s * s;
  #pragma unroll
  for (int off = 32; off > 0; off >>= 1) ss += __shfl_xor(ss, off);
  float shell = s / fmaxf(sqrtf(ss), 1e-12f);
  sm[w][lane] = shell;
  const float q = tanhf(sc[64] + b_charge[0]);
  __syncthreads();
  // proj[r] for r = lane&31 (lanes l and l+32 compute same r redundantly)
  const int r = lane & 31;
  float p = rff_bias[r];
  const float4* om = reinterpret_cast<const float4*>(omega + r * 64);
  const float4* sv = reinterpret_cast<const float4*>(sm[w]);
  #pragma unroll
  for (int d = 0; d < 16; ++d) {
    float4 o4 = om[d], s4 = sv[d];
    p += o4.x * s4.x + o4.y * s4.y + o4.z * s4.z + o4.w * s4.w;
  }
  const float RFFS = 0.13767388f;  // sqrt(2/64)*sqrt(exp(-0.5))
  float phis = (lane < 32) ? cosf(p) * RFFS : sinf(p) * RFFS;
  // mags = sqrt(1/m! + 1e-10)
  float q2 = q * q;
  float pc[5];
  pc[0] = 1.0f;
  pc[1] = q;
  pc[2] = 0.70710678f * q2;
  pc[3] = 0.40824829f * q2 * q;
  pc[4] = 0.20412415f * q2 * q2;
  u16* o = tp + (size_t)row * 320 + lane;
  #pragma unroll
  for (int m = 0; m < 5; ++m) o[m * 64] = f2bf(pc[m] * phis);
}

// ---------------- softmax with Toeplitz weight + causal mask ----------------
__global__ __launch_bounds__(256) void softmax_kernel(
    const float* __restrict__ logits, const float* __restrict__ log_temp,
    u16* __restrict__ attn) {
  __shared__ float rb[8];
  const int rowid = blockIdx.x;
  const int i = rowid & 511;
  const float* L = logits + (size_t)rowid * 512;
  u16* Ar = attn + (size_t)rowid * 512;
  const int t = threadIdx.x, lane = t & 63, w = t >> 6;
  const float invt = 1.0f / (log1pf(expf(log_temp[0])) + 0.1f);
  const int j0 = t, j1 = t + 256;
  float z0 = (j0 <= i) ? L[j0] * expf(-0.03f * (float)(i - j0)) * invt : -INFINITY;
  float z1 = (j1 <= i) ? L[j1] * expf(-0.03f * (float)(i - j1)) * invt : -INFINITY;
  float m = fmaxf(z0, z1);
  #pragma unroll
  for (int off = 32; off > 0; off >>= 1) m = fmaxf(m, __shfl_xor(m, off));
  if (lane == 0) rb[w] = m;
  __syncthreads();
  m = fmaxf(fmaxf(rb[0], rb[1]), fmaxf(rb[2], rb[3]));
  float e0 = expf(z0 - m);   // exp(-inf)=0 for masked
  float e1 = expf(z1 - m);
  float sum = e0 + e1;
  #pragma unroll
  for (int off = 32; off > 0; off >>= 1) sum += __shfl_xor(sum, off);
  if (lane == 0) rb[4 + w] = sum;
  __syncthreads();
  const float inv = 1.0f / (rb[4] + rb[5] + rb[6] + rb[7]);
  Ar[j0] = f2bf(e0 * inv);
  Ar[j1] = f2bf(e1 * inv);
}

extern "C" void kernel_launch(void* const* d_in, const int* in_sizes, int n_in,
                              void* d_out, int out_size, void* d_ws, size_t ws_size,
                              hipStream_t stream) {
  (void)in_sizes; (void)n_in; (void)out_size; (void)ws_size;
  const float* x     = (const float*)d_in[0];
  const float* Wch   = (const float*)d_in[1];
  const float* bch   = (const float*)d_in[2];
  const float* Wsh   = (const float*)d_in[3];
  const float* bsh   = (const float*)d_in[4];
  const float* omega = (const float*)d_in[5];
  const float* rffb  = (const float*)d_in[6];
  const float* Wcb   = (const float*)d_in[7];
  const float* Wv    = (const float*)d_in[8];
  const float* bv    = (const float*)d_in[9];
  const float* Wo    = (const float*)d_in[10];
  const float* bo    = (const float*)d_in[11];
  const float* lt    = (const float*)d_in[12];
  float* out = (float*)d_out;
  char* ws = (char*)d_ws;

  // ws layout (aliased; ~181 MB total)
  u16*   xb   = (u16*)(ws + 0);            // 67,108,864 B; later reused as out2
  u16*   vt   = (u16*)(ws + 67108864);     // 67,108,864 B; early reused as SC (fp32)
  float* sc   = (float*)(ws + 67108864);   // 16.8 MB, dead before vt written
  u16*   attn = (u16*)(ws + 134217728);    // 33.5 MB; early reused as tp
  u16*   tp   = (u16*)(ws + 134217728);    // 21 MB, dead before attn written
  u16*   phi  = (u16*)(ws + 167772160);    // 32768 x 128 bf16
  u16*   wvb  = (u16*)(ws + 176160768);
  u16*   wob  = (u16*)(ws + 178257920);
  u16*   wcat = (u16*)(ws + 180355072);    // 128 x 1024
  u16*   wcbb = (u16*)(ws + 180617216);    // 128 x 320
  float* logits = out;                     // d_out holds logits until final GEMM
  u16*   out2 = xb;                        // xb dead after V GEMM

  convert_x_kernel<<<8192, 256, 0, stream>>>(x, xb, 33554432 / 4);
  prep_weights_kernel<<<8864, 256, 0, stream>>>(Wv, Wo, Wsh, Wch, Wcb, wvb, wob, wcat, wcbb);
  // SC = x @ [Wsh;Wch]^T  (fp32 out)
  gemm_bt<0><<<dim3(1, 256, 1), 256, 0, stream>>>(xb, wcat, nullptr, sc,
      32768, 128, 1024, 1024, 1024, 128, 0, 0, 0);
  features_kernel<<<8192, 256, 0, stream>>>(sc, bsh, bch, omega, rffb, tp);
  // phi = tp @ Wcomb^T (bf16 out, 128 cols, first 64 valid)
  gemm_bt<1><<<dim3(1, 256, 1), 256, 0, stream>>>(tp, wcbb, nullptr, phi,
      32768, 128, 320, 320, 320, 128, 0, 0, 0);
  // logits[b] = phi_b @ phi_b^T (fp32 into d_out)
  gemm_bt<0><<<dim3(4, 4, 64), 256, 0, stream>>>(phi, phi, nullptr, logits,
      512, 512, 64, 128, 128, 512, 65536, 65536, 262144);
  softmax_kernel<<<32768, 256, 0, stream>>>(logits, lt, attn);
  // Vt[o][r] = (x @ Wv^T + bv)^T  (bf16 transposed epilogue)
  gemm_bt<2><<<dim3(8, 256, 1), 256, 0, stream>>>(xb, wvb, bv, vt,
      32768, 1024, 1024, 1024, 1024, 32768, 0, 0, 0);
  // out2[b] = attn_b @ V_b  (Bt = Vt + b*512, ldb = 32768)
  gemm_bt<1><<<dim3(8, 4, 64), 256, 0, stream>>>(attn, vt, nullptr, out2,
      512, 1024, 512, 512, 32768, 1024, 262144, 512, 524288);
  // out = out2 @ Wo^T + bo  (fp32 into d_out)
  gemm_bt<0><<<dim3(8, 256, 1), 256, 0, stream>>>(out2, wob, bo, out,
      32768, 1024, 1024, 1024, 1024, 1024, 0, 0, 0);
}

// Round 2
// 684.913 us; speedup vs baseline: 1.0497x; 1.0497x over previous
//
#include <hip/hip_runtime.h>
#include <hip/hip_bf16.h>
#include <math.h>

// B=64, N=512, D=1024, SHELL=64, RFF=32, ORDER=4, COMBINED=64
// Pipeline: x->bf16; SC=x@[Wsh;Wch]^T; features->tp; phi=tp@Wcomb^T;
// logits=phi@phi^T (batched); softmax(T,causal)->attn(bf16);
// Vt = (x@Wv^T+bv)^T (bf16, transposed epilogue); out2=attn@Vt^T; out=out2@Wo^T+bo.
// R1: gemm_bt staging via global_load_lds width=16 (m97 structure) + XCD chunked swizzle.

using u16 = unsigned short;
typedef short short8 __attribute__((ext_vector_type(8)));   // 8 x bf16 (4 VGPR)
typedef float f32x4 __attribute__((ext_vector_type(4)));

__device__ __forceinline__ u16 f2bf(float f) {
  unsigned u = __float_as_uint(f);
  return (u16)((u + 0x7fffu + ((u >> 16) & 1u)) >> 16);   // RNE
}

// async global->LDS, 16B per lane; lds dest is wave-uniform base + lane*16
__device__ __forceinline__ void gload16(const u16* g, u16* l) {
  __builtin_amdgcn_global_load_lds(
      (const __attribute__((address_space(1))) unsigned int*)(g),
      (__attribute__((address_space(3))) unsigned int*)(l),
      16, 0, 0);
}

// ---------------- x -> bf16 ----------------
__global__ __launch_bounds__(256) void convert_x_kernel(const float* __restrict__ in,
                                                        u16* __restrict__ out, int n4) {
  int idx = blockIdx.x * 256 + threadIdx.x;
  int stride = gridDim.x * 256;
  for (int i = idx; i < n4; i += stride) {
    float4 v = reinterpret_cast<const float4*>(in)[i];
    ushort4 o;
    o.x = f2bf(v.x); o.y = f2bf(v.y); o.z = f2bf(v.z); o.w = f2bf(v.w);
    reinterpret_cast<ushort4*>(out)[i] = o;
  }
}

// ---------------- weights -> bf16 (Wv, Wo, Wcat=[Wsh;Wch;0], Wcomb padded to 128 rows) ----
__global__ __launch_bounds__(256) void prep_weights_kernel(
    const float* __restrict__ Wv, const float* __restrict__ Wo,
    const float* __restrict__ Wsh, const float* __restrict__ Wch,
    const float* __restrict__ Wcb,
    u16* __restrict__ wvb, u16* __restrict__ wob,
    u16* __restrict__ wcat, u16* __restrict__ wcbb) {
  int i = blockIdx.x * 256 + threadIdx.x;
  if (i < 1048576) { wvb[i] = f2bf(Wv[i]); return; }
  i -= 1048576;
  if (i < 1048576) { wob[i] = f2bf(Wo[i]); return; }
  i -= 1048576;
  if (i < 131072) {  // Wcat: 128 rows x 1024 (rows 0-63 Wsh, row 64 Wch, rest 0)
    int row = i >> 10, e = i & 1023;
    float v = (row < 64) ? Wsh[i] : ((row == 64) ? Wch[e] : 0.0f);
    wcat[i] = f2bf(v);
    return;
  }
  i -= 131072;
  if (i < 40960) {   // Wcomb padded: 128 rows x 320
    int row = i / 320;
    wcbb[i] = f2bf(row < 64 ? Wcb[i] : 0.0f);
  }
}

// ---------------- generic bf16 MFMA GEMM: C = A @ Bt^T (+bias[n]) --------------
// A: M x K (lda), Bt: N x K (ldb), both row-major K-contiguous, all mult-of-tile.
// OUT_MODE: 0 = fp32 C[m*ldc+n], 1 = bf16 C[m*ldc+n], 2 = bf16 transposed C[n*ldc+m].
template<int OUT_MODE>
__global__ __launch_bounds__(256) void gemm_bt(
    const u16* __restrict__ A, const u16* __restrict__ Bt,
    const float* __restrict__ bias, void* __restrict__ Cv,
    int M, int N, int K, int lda, int ldb, int ldc,
    long long sA, long long sB, long long sC) {
  (void)M; (void)N;
  __shared__ u16 lA[128 * 32];
  __shared__ u16 lB[128 * 32];
  const int t = threadIdx.x;
  const int lane = t & 63;
  const int w = t >> 6;
  const u16* Ag = A + (size_t)blockIdx.z * sA;
  const u16* Bg = Bt + (size_t)blockIdx.z * sB;

  // XCD chunked swizzle on the x-y plane (bijective: all our grids %8==0)
  int gx = gridDim.x, gy = gridDim.y;
  int bid = blockIdx.y * gx + blockIdx.x;
  int nwg = gx * gy;
  if ((nwg & 7) == 0) {
    int cpx = nwg >> 3;
    bid = (bid & 7) * cpx + (bid >> 3);
  }
  const int m0 = (bid / gx) * 128;
  const int n0 = (bid % gx) * 128;

  const int wm = (w >> 1) * 64;   // 2x2 waves, 64x64 each
  const int wn = (w & 1) * 64;
  const int rl = lane & 15;
  const int kl = (lane >> 4) * 8;

  // staging geometry: wave w stages rows [w*32, w*32+32) of each 128x32 tile,
  // two calls of 16 rows each; lane l -> row +(l>>2), col (l&3)*8.
  const int rs = w * 32 + (lane >> 2);
  const int cs = (lane & 3) * 8;
  u16* ldsA = &lA[w * 1024];      // 32 rows * 32 cols
  u16* ldsB = &lB[w * 1024];

  f32x4 acc[4][4] = {};

  for (int k0 = 0; k0 < K; k0 += 32) {
    const u16* ga = Ag + (size_t)(m0 + rs) * lda + k0 + cs;
    const u16* gb = Bg + (size_t)(n0 + rs) * ldb + k0 + cs;
    gload16(ga,                      ldsA);
    gload16(ga + (size_t)16 * lda,   ldsA + 512);
    gload16(gb,                      ldsB);
    gload16(gb + (size_t)16 * ldb,   ldsB + 512);
    __syncthreads();   // drains vmcnt(0): staged data visible
    short8 af[4], bfr[4];
    #pragma unroll
    for (int mi = 0; mi < 4; ++mi)
      af[mi] = *reinterpret_cast<const short8*>(&lA[(wm + mi * 16 + rl) * 32 + kl]);
    #pragma unroll
    for (int ni = 0; ni < 4; ++ni)
      bfr[ni] = *reinterpret_cast<const short8*>(&lB[(wn + ni * 16 + rl) * 32 + kl]);
    #pragma unroll
    for (int mi = 0; mi < 4; ++mi) {
      #pragma unroll
      for (int ni = 0; ni < 4; ++ni)
        acc[mi][ni] = __builtin_amdgcn_mfma_f32_16x16x32_bf16(af[mi], bfr[ni], acc[mi][ni], 0, 0, 0);
    }
    __syncthreads();
  }

  // C/D layout: col = lane&15, row = (lane>>4)*4 + reg  [guide §3, m89/m91 verified]
  const int cm = (lane >> 4) * 4;
  #pragma unroll
  for (int mi = 0; mi < 4; ++mi) {
    #pragma unroll
    for (int ni = 0; ni < 4; ++ni) {
      const int gm = m0 + wm + mi * 16 + cm;
      const int gn = n0 + wn + ni * 16 + rl;
      const float bsv = bias ? bias[gn] : 0.0f;
      if (OUT_MODE == 0) {
        float* C = (float*)Cv + (size_t)blockIdx.z * sC;
        #pragma unroll
        for (int r = 0; r < 4; ++r)
          C[(size_t)(gm + r) * ldc + gn] = acc[mi][ni][r] + bsv;
      } else if (OUT_MODE == 1) {
        u16* C = (u16*)Cv + (size_t)blockIdx.z * sC;
        #pragma unroll
        for (int r = 0; r < 4; ++r)
          C[(size_t)(gm + r) * ldc + gn] = f2bf(acc[mi][ni][r] + bsv);
      } else {
        u16* C = (u16*)Cv + (size_t)blockIdx.z * sC;
        ushort4 pk;
        pk.x = f2bf(acc[mi][ni][0] + bsv);
        pk.y = f2bf(acc[mi][ni][1] + bsv);
        pk.z = f2bf(acc[mi][ni][2] + bsv);
        pk.w = f2bf(acc[mi][ni][3] + bsv);
        *reinterpret_cast<ushort4*>(&C[(size_t)gn * ldc + gm]) = pk;
      }
    }
  }
}

// ---------------- features: SC(fp32 32768x128) -> tp(bf16 32768x320) ----------------
__global__ __launch_bounds__(256) void features_kernel(
    const float* __restrict__ SC, const float* __restrict__ b_shell,
    const float* __restrict__ b_charge, const float* __restrict__ omega,
    const float* __restrict__ rff_bias, u16* __restrict__ tp) {
  __shared__ __align__(16) float sm[4][64];
  const int lane = threadIdx.x & 63;
  const int w = threadIdx.x >> 6;
  const int row = blockIdx.x * 4 + w;
  const float* sc = SC + (size_t)row * 128;
  float s = sc[lane] + b_shell[lane];
  float ss = s * s;
  #pragma unroll
  for (int off = 32; off > 0; off >>= 1) ss += __shfl_xor(ss, off);
  float shell = s / fmaxf(sqrtf(ss), 1e-12f);
  sm[w][lane] = shell;
  const float q = tanhf(sc[64] + b_charge[0]);
  __syncthreads();
  const int r = lane & 31;
  float p = rff_bias[r];
  const float4* om = reinterpret_cast<const float4*>(omega + r * 64);
  const float4* sv = reinterpret_cast<const float4*>(sm[w]);
  #pragma unroll
  for (int d = 0; d < 16; ++d) {
    float4 o4 = om[d], s4 = sv[d];
    p += o4.x * s4.x + o4.y * s4.y + o4.z * s4.z + o4.w * s4.w;
  }
  const float RFFS = 0.13767388f;  // sqrt(2/64)*sqrt(exp(-0.5))
  float phis = (lane < 32) ? cosf(p) * RFFS : sinf(p) * RFFS;
  float q2 = q * q;
  float pc[5];
  pc[0] = 1.0f;
  pc[1] = q;
  pc[2] = 0.70710678f * q2;
  pc[3] = 0.40824829f * q2 * q;
  pc[4] = 0.20412415f * q2 * q2;
  u16* o = tp + (size_t)row * 320 + lane;
  #pragma unroll
  for (int m = 0; m < 5; ++m) o[m * 64] = f2bf(pc[m] * phis);
}

// ---------------- softmax with Toeplitz weight + causal mask ----------------
__global__ __launch_bounds__(256) void softmax_kernel(
    const float* __restrict__ logits, const float* __restrict__ log_temp,
    u16* __restrict__ attn) {
  __shared__ float rb[8];
  const int rowid = blockIdx.x;
  const int i = rowid & 511;
  const float* L = logits + (size_t)rowid * 512;
  u16* Ar = attn + (size_t)rowid * 512;
  const int t = threadIdx.x, lane = t & 63, w = t >> 6;
  const float invt = 1.0f / (log1pf(expf(log_temp[0])) + 0.1f);
  const int j0 = t, j1 = t + 256;
  float z0 = (j0 <= i) ? L[j0] * expf(-0.03f * (float)(i - j0)) * invt : -INFINITY;
  float z1 = (j1 <= i) ? L[j1] * expf(-0.03f * (float)(i - j1)) * invt : -INFINITY;
  float m = fmaxf(z0, z1);
  #pragma unroll
  for (int off = 32; off > 0; off >>= 1) m = fmaxf(m, __shfl_xor(m, off));
  if (lane == 0) rb[w] = m;
  __syncthreads();
  m = fmaxf(fmaxf(rb[0], rb[1]), fmaxf(rb[2], rb[3]));
  float e0 = expf(z0 - m);
  float e1 = expf(z1 - m);
  float sum = e0 + e1;
  #pragma unroll
  for (int off = 32; off > 0; off >>= 1) sum += __shfl_xor(sum, off);
  if (lane == 0) rb[4 + w] = sum;
  __syncthreads();
  const float inv = 1.0f / (rb[4] + rb[5] + rb[6] + rb[7]);
  Ar[j0] = f2bf(e0 * inv);
  Ar[j1] = f2bf(e1 * inv);
}

extern "C" void kernel_launch(void* const* d_in, const int* in_sizes, int n_in,
                              void* d_out, int out_size, void* d_ws, size_t ws_size,
                              hipStream_t stream) {
  (void)in_sizes; (void)n_in; (void)out_size; (void)ws_size;
  const float* x     = (const float*)d_in[0];
  const float* Wch   = (const float*)d_in[1];
  const float* bch   = (const float*)d_in[2];
  const float* Wsh   = (const float*)d_in[3];
  const float* bsh   = (const float*)d_in[4];
  const float* omega = (const float*)d_in[5];
  const float* rffb  = (const float*)d_in[6];
  const float* Wcb   = (const float*)d_in[7];
  const float* Wv    = (const float*)d_in[8];
  const float* bv    = (const float*)d_in[9];
  const float* Wo    = (const float*)d_in[10];
  const float* bo    = (const float*)d_in[11];
  const float* lt    = (const float*)d_in[12];
  float* out = (float*)d_out;
  char* ws = (char*)d_ws;

  // ws layout (aliased; ~181 MB total)
  u16*   xb   = (u16*)(ws + 0);            // later reused as out2
  u16*   vt   = (u16*)(ws + 67108864);     // early reused as SC (fp32)
  float* sc   = (float*)(ws + 67108864);   // dead before vt written
  u16*   attn = (u16*)(ws + 134217728);    // early reused as tp
  u16*   tp   = (u16*)(ws + 134217728);    // dead before attn written
  u16*   phi  = (u16*)(ws + 167772160);    // 32768 x 128 bf16
  u16*   wvb  = (u16*)(ws + 176160768);
  u16*   wob  = (u16*)(ws + 178257920);
  u16*   wcat = (u16*)(ws + 180355072);    // 128 x 1024
  u16*   wcbb = (u16*)(ws + 180617216);    // 128 x 320
  float* logits = out;                     // d_out holds logits until final GEMM
  u16*   out2 = xb;

  convert_x_kernel<<<8192, 256, 0, stream>>>(x, xb, 33554432 / 4);
  prep_weights_kernel<<<8864, 256, 0, stream>>>(Wv, Wo, Wsh, Wch, Wcb, wvb, wob, wcat, wcbb);
  // SC = x @ [Wsh;Wch]^T  (fp32 out)
  gemm_bt<0><<<dim3(1, 256, 1), 256, 0, stream>>>(xb, wcat, nullptr, sc,
      32768, 128, 1024, 1024, 1024, 128, 0, 0, 0);
  features_kernel<<<8192, 256, 0, stream>>>(sc, bsh, bch, omega, rffb, tp);
  // phi = tp @ Wcomb^T (bf16 out, 128 cols, first 64 valid)
  gemm_bt<1><<<dim3(1, 256, 1), 256, 0, stream>>>(tp, wcbb, nullptr, phi,
      32768, 128, 320, 320, 320, 128, 0, 0, 0);
  // logits[b] = phi_b @ phi_b^T (fp32 into d_out)
  gemm_bt<0><<<dim3(4, 4, 64), 256, 0, stream>>>(phi, phi, nullptr, logits,
      512, 512, 64, 128, 128, 512, 65536, 65536, 262144);
  softmax_kernel<<<32768, 256, 0, stream>>>(logits, lt, attn);
  // Vt[o][r] = (x @ Wv^T + bv)^T  (bf16 transposed epilogue)
  gemm_bt<2><<<dim3(8, 256, 1), 256, 0, stream>>>(xb, wvb, bv, vt,
      32768, 1024, 1024, 1024, 1024, 32768, 0, 0, 0);
  // out2[b] = attn_b @ V_b  (Bt = Vt + b*512, ldb = 32768)
  gemm_bt<1><<<dim3(8, 4, 64), 256, 0, stream>>>(attn, vt, nullptr, out2,
      512, 1024, 512, 512, 32768, 1024, 262144, 512, 524288);
  // out = out2 @ Wo^T + bo  (fp32 into d_out)
  gemm_bt<0><<<dim3(8, 256, 1), 256, 0, stream>>>(out2, wob, bo, out,
      32768, 1024, 1024, 1024, 1024, 1024, 0, 0, 0);
}

// Round 3
// 635.234 us; speedup vs baseline: 1.1318x; 1.0782x over previous
//
#include <hip/hip_runtime.h>
#include <hip/hip_bf16.h>
#include <math.h>

// B=64, N=512, D=1024, SHELL=64, RFF=32, ORDER=4, COMBINED=64
// R2: gemm256 (256x256 tile, BK=64, 8 waves, dbuf LDS, counted vmcnt, T2 XOR
// swizzle, T5 setprio) for the three big GEMMs; 128-tile gemm_bt for the rest.

using u16 = unsigned short;
typedef short short8 __attribute__((ext_vector_type(8)));   // 8 x bf16 (4 VGPR)
typedef float f32x4 __attribute__((ext_vector_type(4)));

__device__ __forceinline__ u16 f2bf(float f) {
  unsigned u = __float_as_uint(f);
  return (u16)((u + 0x7fffu + ((u >> 16) & 1u)) >> 16);   // RNE
}

// async global->LDS, 16B per lane; lds dest = wave-uniform base + lane*16
__device__ __forceinline__ void gload16(const u16* g, const u16* l) {
  __builtin_amdgcn_global_load_lds(
      (const __attribute__((address_space(1))) unsigned int*)(g),
      (__attribute__((address_space(3))) unsigned int*)(l),
      16, 0, 0);
}

// swizzled LDS read: row stride 128B, byte-in-row b XORed by (row&7)<<4
__device__ __forceinline__ short8 ldsrd(const u16* base, int row, int b) {
  int byte = row * 128 + (b ^ ((row & 7) << 4));
  return *reinterpret_cast<const short8*>(reinterpret_cast<const char*>(base) + byte);
}

// ---------------- x -> bf16 ----------------
__global__ __launch_bounds__(256) void convert_x_kernel(const float* __restrict__ in,
                                                        u16* __restrict__ out, int n4) {
  int idx = blockIdx.x * 256 + threadIdx.x;
  int stride = gridDim.x * 256;
  for (int i = idx; i < n4; i += stride) {
    float4 v = reinterpret_cast<const float4*>(in)[i];
    ushort4 o;
    o.x = f2bf(v.x); o.y = f2bf(v.y); o.z = f2bf(v.z); o.w = f2bf(v.w);
    reinterpret_cast<ushort4*>(out)[i] = o;
  }
}

// ---------------- weights -> bf16 ----------------
__global__ __launch_bounds__(256) void prep_weights_kernel(
    const float* __restrict__ Wv, const float* __restrict__ Wo,
    const float* __restrict__ Wsh, const float* __restrict__ Wch,
    const float* __restrict__ Wcb,
    u16* __restrict__ wvb, u16* __restrict__ wob,
    u16* __restrict__ wcat, u16* __restrict__ wcbb) {
  int i = blockIdx.x * 256 + threadIdx.x;
  if (i < 1048576) { wvb[i] = f2bf(Wv[i]); return; }
  i -= 1048576;
  if (i < 1048576) { wob[i] = f2bf(Wo[i]); return; }
  i -= 1048576;
  if (i < 131072) {  // Wcat: 128 rows x 1024 (rows 0-63 Wsh, row 64 Wch, rest 0)
    int row = i >> 10, e = i & 1023;
    float v = (row < 64) ? Wsh[i] : ((row == 64) ? Wch[e] : 0.0f);
    wcat[i] = f2bf(v);
    return;
  }
  i -= 131072;
  if (i < 40960) {   // Wcomb padded: 128 rows x 320
    int row = i / 320;
    wcbb[i] = f2bf(row < 64 ? Wcb[i] : 0.0f);
  }
}

// ================= gemm256: C = A @ Bt^T (+bias), 256x256 tile =================
// A: M x K (lda), Bt: N x K (ldb), K-contiguous. M%256==0, N%256==0, K%64==0, K>=128.
// OUT_MODE: 0 fp32 C[m*ldc+n], 1 bf16 C[m*ldc+n], 2 bf16 transposed C[n*ldc+m].
template<int OUT_MODE>
__global__ __launch_bounds__(512, 2) void gemm256(
    const u16* __restrict__ A, const u16* __restrict__ Bt,
    const float* __restrict__ bias, void* __restrict__ Cv,
    int M, int N, int K, int lda, int ldb, int ldc,
    long long sA, long long sB, long long sC) {
  (void)M; (void)N;
  __shared__ u16 lds[65536];   // 128 KiB: [buf0 A|B][buf1 A|B], 32KB each
  const int t = threadIdx.x;
  const int lane = t & 63;
  const int w = t >> 6;
  const u16* Ag = A + (size_t)blockIdx.z * sA;
  const u16* Bg = Bt + (size_t)blockIdx.z * sB;

  // XCD chunked swizzle on x-y plane (bijective when nwg%8==0)
  int gx = gridDim.x, gy = gridDim.y;
  int bid = blockIdx.y * gx + blockIdx.x;
  int nwg = gx * gy;
  if ((nwg & 7) == 0) { int cpx = nwg >> 3; bid = (bid & 7) * cpx + (bid >> 3); }
  const int m0 = (bid / gx) * 256;
  const int n0 = (bid % gx) * 256;

  const int wm = w >> 2;          // 2 wave-rows x 4 wave-cols; per-wave out 128x64
  const int wn = w & 3;
  const int rl = lane & 15;
  const int kq = lane >> 4;       // 16B chunk within 64B k-half

  // staging: per tile 8 gloads (A g=0..3, B g=0..3); wave w covers rows g*64+w*8+(lane>>3)
  // source col pre-swizzled so linear LDS dest holds the XOR-swizzled layout
  const int srow = w * 8 + (lane >> 3);
  const int scol = 8 * ((lane & 7) ^ ((lane >> 3) & 7));
  const u16* aS = Ag + (size_t)(m0 + srow) * lda + scol;
  const u16* bS = Bg + (size_t)(n0 + srow) * ldb + scol;

  const int NT = K >> 6;

  // prologue: stage tile 0 -> buf0
  #pragma unroll
  for (int g = 0; g < 4; ++g) {
    gload16(aS + (size_t)(g * 64) * lda, lds + w * 512 + g * 4096);
    gload16(bS + (size_t)(g * 64) * ldb, lds + 16384 + w * 512 + g * 4096);
  }

  f32x4 acc[8][4] = {};

  for (int tt = 0; tt < NT; ++tt) {
    const int c = tt & 1, nc = c ^ 1;
    const u16* At  = lds + c * 32768;
    const u16* Btl = At + 16384;
    const u16* dA  = lds + nc * 32768 + w * 512;
    const u16* dB  = dA + 16384;
    const int kn = (tt + 1 < NT ? tt + 1 : 0) << 6;   // prefetch clamp (last iter: dummy)

    __builtin_amdgcn_s_barrier();        // all waves done reading buf nc (prev tile)
    #pragma unroll
    for (int g = 0; g < 4; ++g) {
      gload16(aS + (size_t)(g * 64) * lda + kn, dA + g * 4096);
      gload16(bS + (size_t)(g * 64) * ldb + kn, dB + g * 4096);
    }
    asm volatile("s_waitcnt vmcnt(8)" ::: "memory");  // tile tt landed (8 newest = prefetch)
    __builtin_amdgcn_s_barrier();        // every wave certified its own loads -> tile complete
    __builtin_amdgcn_sched_barrier(0);

    short8 bq[4][2];
    #pragma unroll
    for (int p = 0; p < 4; ++p) {        // 4 phases x 16 MFMA
      if (p == 0) {
        #pragma unroll
        for (int ni = 0; ni < 4; ++ni)
          #pragma unroll
          for (int ks = 0; ks < 2; ++ks)
            bq[ni][ks] = ldsrd(Btl, wn * 64 + ni * 16 + rl, ks * 64 + kq * 16);
      }
      short8 a0k0 = ldsrd(At, wm * 128 + (2 * p + 0) * 16 + rl, 0 + kq * 16);
      short8 a0k1 = ldsrd(At, wm * 128 + (2 * p + 0) * 16 + rl, 64 + kq * 16);
      short8 a1k0 = ldsrd(At, wm * 128 + (2 * p + 1) * 16 + rl, 0 + kq * 16);
      short8 a1k1 = ldsrd(At, wm * 128 + (2 * p + 1) * 16 + rl, 64 + kq * 16);
      __builtin_amdgcn_s_setprio(1);
      #pragma unroll
      for (int ni = 0; ni < 4; ++ni) {
        acc[2 * p][ni]     = __builtin_amdgcn_mfma_f32_16x16x32_bf16(a0k0, bq[ni][0], acc[2 * p][ni], 0, 0, 0);
        acc[2 * p][ni]     = __builtin_amdgcn_mfma_f32_16x16x32_bf16(a0k1, bq[ni][1], acc[2 * p][ni], 0, 0, 0);
        acc[2 * p + 1][ni] = __builtin_amdgcn_mfma_f32_16x16x32_bf16(a1k0, bq[ni][0], acc[2 * p + 1][ni], 0, 0, 0);
        acc[2 * p + 1][ni] = __builtin_amdgcn_mfma_f32_16x16x32_bf16(a1k1, bq[ni][1], acc[2 * p + 1][ni], 0, 0, 0);
      }
      __builtin_amdgcn_s_setprio(0);
    }
  }

  // C/D layout: col = lane&15, row = (lane>>4)*4 + reg
  const int cm = (lane >> 4) * 4;
  #pragma unroll
  for (int mi = 0; mi < 8; ++mi) {
    #pragma unroll
    for (int ni = 0; ni < 4; ++ni) {
      const int gm = m0 + wm * 128 + mi * 16 + cm;
      const int gn = n0 + wn * 64 + ni * 16 + rl;
      const float bsv = bias ? bias[gn] : 0.0f;
      if (OUT_MODE == 0) {
        float* C = (float*)Cv + (size_t)blockIdx.z * sC;
        #pragma unroll
        for (int r = 0; r < 4; ++r)
          C[(size_t)(gm + r) * ldc + gn] = acc[mi][ni][r] + bsv;
      } else if (OUT_MODE == 1) {
        u16* C = (u16*)Cv + (size_t)blockIdx.z * sC;
        #pragma unroll
        for (int r = 0; r < 4; ++r)
          C[(size_t)(gm + r) * ldc + gn] = f2bf(acc[mi][ni][r] + bsv);
      } else {
        u16* C = (u16*)Cv + (size_t)blockIdx.z * sC;
        ushort4 pk;
        pk.x = f2bf(acc[mi][ni][0] + bsv);
        pk.y = f2bf(acc[mi][ni][1] + bsv);
        pk.z = f2bf(acc[mi][ni][2] + bsv);
        pk.w = f2bf(acc[mi][ni][3] + bsv);
        *reinterpret_cast<ushort4*>(&C[(size_t)gn * ldc + gm]) = pk;
      }
    }
  }
}

// ---------------- 128-tile GEMM (small shapes: SC, phi, logits) ----------------
template<int OUT_MODE>
__global__ __launch_bounds__(256) void gemm_bt(
    const u16* __restrict__ A, const u16* __restrict__ Bt,
    const float* __restrict__ bias, void* __restrict__ Cv,
    int M, int N, int K, int lda, int ldb, int ldc,
    long long sA, long long sB, long long sC) {
  (void)M; (void)N;
  __shared__ u16 lA[128 * 32];
  __shared__ u16 lB[128 * 32];
  const int t = threadIdx.x;
  const int lane = t & 63;
  const int w = t >> 6;
  const u16* Ag = A + (size_t)blockIdx.z * sA;
  const u16* Bg = Bt + (size_t)blockIdx.z * sB;

  int gx = gridDim.x, gy = gridDim.y;
  int bid = blockIdx.y * gx + blockIdx.x;
  int nwg = gx * gy;
  if ((nwg & 7) == 0) { int cpx = nwg >> 3; bid = (bid & 7) * cpx + (bid >> 3); }
  const int m0 = (bid / gx) * 128;
  const int n0 = (bid % gx) * 128;

  const int wm = (w >> 1) * 64;
  const int wn = (w & 1) * 64;
  const int rl = lane & 15;
  const int kl = (lane >> 4) * 8;
  const int rs = w * 32 + (lane >> 2);
  const int cs = (lane & 3) * 8;
  u16* ldsA = &lA[w * 1024];
  u16* ldsB = &lB[w * 1024];

  f32x4 acc[4][4] = {};

  for (int k0 = 0; k0 < K; k0 += 32) {
    const u16* ga = Ag + (size_t)(m0 + rs) * lda + k0 + cs;
    const u16* gb = Bg + (size_t)(n0 + rs) * ldb + k0 + cs;
    gload16(ga,                    ldsA);
    gload16(ga + (size_t)16 * lda, ldsA + 512);
    gload16(gb,                    ldsB);
    gload16(gb + (size_t)16 * ldb, ldsB + 512);
    __syncthreads();
    short8 af[4], bfr[4];
    #pragma unroll
    for (int mi = 0; mi < 4; ++mi)
      af[mi] = *reinterpret_cast<const short8*>(&lA[(wm + mi * 16 + rl) * 32 + kl]);
    #pragma unroll
    for (int ni = 0; ni < 4; ++ni)
      bfr[ni] = *reinterpret_cast<const short8*>(&lB[(wn + ni * 16 + rl) * 32 + kl]);
    #pragma unroll
    for (int mi = 0; mi < 4; ++mi) {
      #pragma unroll
      for (int ni = 0; ni < 4; ++ni)
        acc[mi][ni] = __builtin_amdgcn_mfma_f32_16x16x32_bf16(af[mi], bfr[ni], acc[mi][ni], 0, 0, 0);
    }
    __syncthreads();
  }

  const int cm = (lane >> 4) * 4;
  #pragma unroll
  for (int mi = 0; mi < 4; ++mi) {
    #pragma unroll
    for (int ni = 0; ni < 4; ++ni) {
      const int gm = m0 + wm + mi * 16 + cm;
      const int gn = n0 + wn + ni * 16 + rl;
      const float bsv = bias ? bias[gn] : 0.0f;
      if (OUT_MODE == 0) {
        float* C = (float*)Cv + (size_t)blockIdx.z * sC;
        #pragma unroll
        for (int r = 0; r < 4; ++r)
          C[(size_t)(gm + r) * ldc + gn] = acc[mi][ni][r] + bsv;
      } else if (OUT_MODE == 1) {
        u16* C = (u16*)Cv + (size_t)blockIdx.z * sC;
        #pragma unroll
        for (int r = 0; r < 4; ++r)
          C[(size_t)(gm + r) * ldc + gn] = f2bf(acc[mi][ni][r] + bsv);
      } else {
        u16* C = (u16*)Cv + (size_t)blockIdx.z * sC;
        ushort4 pk;
        pk.x = f2bf(acc[mi][ni][0] + bsv);
        pk.y = f2bf(acc[mi][ni][1] + bsv);
        pk.z = f2bf(acc[mi][ni][2] + bsv);
        pk.w = f2bf(acc[mi][ni][3] + bsv);
        *reinterpret_cast<ushort4*>(&C[(size_t)gn * ldc + gm]) = pk;
      }
    }
  }
}

// ---------------- features: SC(fp32 32768x128) -> tp(bf16 32768x320) ----------------
__global__ __launch_bounds__(256) void features_kernel(
    const float* __restrict__ SC, const float* __restrict__ b_shell,
    const float* __restrict__ b_charge, const float* __restrict__ omega,
    const float* __restrict__ rff_bias, u16* __restrict__ tp) {
  __shared__ __align__(16) float sm[4][64];
  const int lane = threadIdx.x & 63;
  const int w = threadIdx.x >> 6;
  const int row = blockIdx.x * 4 + w;
  const float* sc = SC + (size_t)row * 128;
  float s = sc[lane] + b_shell[lane];
  float ss = s * s;
  #pragma unroll
  for (int off = 32; off > 0; off >>= 1) ss += __shfl_xor(ss, off);
  float shell = s / fmaxf(sqrtf(ss), 1e-12f);
  sm[w][lane] = shell;
  const float q = tanhf(sc[64] + b_charge[0]);
  __syncthreads();
  const int r = lane & 31;
  float p = rff_bias[r];
  const float4* om = reinterpret_cast<const float4*>(omega + r * 64);
  const float4* sv = reinterpret_cast<const float4*>(sm[w]);
  #pragma unroll
  for (int d = 0; d < 16; ++d) {
    float4 o4 = om[d], s4 = sv[d];
    p += o4.x * s4.x + o4.y * s4.y + o4.z * s4.z + o4.w * s4.w;
  }
  const float RFFS = 0.13767388f;  // sqrt(2/64)*sqrt(exp(-0.5))
  float phis = (lane < 32) ? cosf(p) * RFFS : sinf(p) * RFFS;
  float q2 = q * q;
  float pc[5];
  pc[0] = 1.0f;
  pc[1] = q;
  pc[2] = 0.70710678f * q2;
  pc[3] = 0.40824829f * q2 * q;
  pc[4] = 0.20412415f * q2 * q2;
  u16* o = tp + (size_t)row * 320 + lane;
  #pragma unroll
  for (int m = 0; m < 5; ++m) o[m * 64] = f2bf(pc[m] * phis);
}

// ---------------- softmax with Toeplitz weight + causal mask ----------------
__global__ __launch_bounds__(256) void softmax_kernel(
    const float* __restrict__ logits, const float* __restrict__ log_temp,
    u16* __restrict__ attn) {
  __shared__ float rb[8];
  const int rowid = blockIdx.x;
  const int i = rowid & 511;
  const float* L = logits + (size_t)rowid * 512;
  u16* Ar = attn + (size_t)rowid * 512;
  const int t = threadIdx.x, lane = t & 63, w = t >> 6;
  const float invt = 1.0f / (log1pf(expf(log_temp[0])) + 0.1f);
  const int j0 = t, j1 = t + 256;
  float z0 = (j0 <= i) ? L[j0] * expf(-0.03f * (float)(i - j0)) * invt : -INFINITY;
  float z1 = (j1 <= i) ? L[j1] * expf(-0.03f * (float)(i - j1)) * invt : -INFINITY;
  float m = fmaxf(z0, z1);
  #pragma unroll
  for (int off = 32; off > 0; off >>= 1) m = fmaxf(m, __shfl_xor(m, off));
  if (lane == 0) rb[w] = m;
  __syncthreads();
  m = fmaxf(fmaxf(rb[0], rb[1]), fmaxf(rb[2], rb[3]));
  float e0 = expf(z0 - m);
  float e1 = expf(z1 - m);
  float sum = e0 + e1;
  #pragma unroll
  for (int off = 32; off > 0; off >>= 1) sum += __shfl_xor(sum, off);
  if (lane == 0) rb[4 + w] = sum;
  __syncthreads();
  const float inv = 1.0f / (rb[4] + rb[5] + rb[6] + rb[7]);
  Ar[j0] = f2bf(e0 * inv);
  Ar[j1] = f2bf(e1 * inv);
}

extern "C" void kernel_launch(void* const* d_in, const int* in_sizes, int n_in,
                              void* d_out, int out_size, void* d_ws, size_t ws_size,
                              hipStream_t stream) {
  (void)in_sizes; (void)n_in; (void)out_size; (void)ws_size;
  const float* x     = (const float*)d_in[0];
  const float* Wch   = (const float*)d_in[1];
  const float* bch   = (const float*)d_in[2];
  const float* Wsh   = (const float*)d_in[3];
  const float* bsh   = (const float*)d_in[4];
  const float* omega = (const float*)d_in[5];
  const float* rffb  = (const float*)d_in[6];
  const float* Wcb   = (const float*)d_in[7];
  const float* Wv    = (const float*)d_in[8];
  const float* bv    = (const float*)d_in[9];
  const float* Wo    = (const float*)d_in[10];
  const float* bo    = (const float*)d_in[11];
  const float* lt    = (const float*)d_in[12];
  float* out = (float*)d_out;
  char* ws = (char*)d_ws;

  // ws layout (aliased; ~181 MB total)
  u16*   xb   = (u16*)(ws + 0);            // later reused as out2
  u16*   vt   = (u16*)(ws + 67108864);     // early reused as SC (fp32)
  float* sc   = (float*)(ws + 67108864);   // dead before vt written
  u16*   attn = (u16*)(ws + 134217728);    // early reused as tp
  u16*   tp   = (u16*)(ws + 134217728);    // dead before attn written
  u16*   phi  = (u16*)(ws + 167772160);    // 32768 x 128 bf16
  u16*   wvb  = (u16*)(ws + 176160768);
  u16*   wob  = (u16*)(ws + 178257920);
  u16*   wcat = (u16*)(ws + 180355072);    // 128 x 1024
  u16*   wcbb = (u16*)(ws + 180617216);    // 128 x 320
  float* logits = out;                     // d_out holds logits until final GEMM
  u16*   out2 = xb;

  convert_x_kernel<<<8192, 256, 0, stream>>>(x, xb, 33554432 / 4);
  prep_weights_kernel<<<8864, 256, 0, stream>>>(Wv, Wo, Wsh, Wch, Wcb, wvb, wob, wcat, wcbb);
  // SC = x @ [Wsh;Wch]^T  (fp32 out)
  gemm_bt<0><<<dim3(1, 256, 1), 256, 0, stream>>>(xb, wcat, nullptr, sc,
      32768, 128, 1024, 1024, 1024, 128, 0, 0, 0);
  features_kernel<<<8192, 256, 0, stream>>>(sc, bsh, bch, omega, rffb, tp);
  // phi = tp @ Wcomb^T (bf16 out, 128 cols, first 64 valid)
  gemm_bt<1><<<dim3(1, 256, 1), 256, 0, stream>>>(tp, wcbb, nullptr, phi,
      32768, 128, 320, 320, 320, 128, 0, 0, 0);
  // logits[b] = phi_b @ phi_b^T (fp32 into d_out)
  gemm_bt<0><<<dim3(4, 4, 64), 256, 0, stream>>>(phi, phi, nullptr, logits,
      512, 512, 64, 128, 128, 512, 65536, 65536, 262144);
  softmax_kernel<<<32768, 256, 0, stream>>>(logits, lt, attn);
  // Vt[d][tok] = (x @ Wv^T + bv)^T  (bf16 transposed epilogue, 256-tile pipelined)
  gemm256<2><<<dim3(4, 128, 1), 512, 0, stream>>>(xb, wvb, bv, vt,
      32768, 1024, 1024, 1024, 1024, 32768, 0, 0, 0);
  // out2[b] = attn_b @ V_b  (Bt = Vt + b*512, ldb = 32768)
  gemm256<1><<<dim3(4, 2, 64), 512, 0, stream>>>(attn, vt, nullptr, out2,
      512, 1024, 512, 512, 32768, 1024, 262144, 512, 524288);
  // out = out2 @ Wo^T + bo  (fp32 into d_out)
  gemm256<0><<<dim3(4, 128, 1), 512, 0, stream>>>(out2, wob, bo, out,
      32768, 1024, 1024, 1024, 1024, 1024, 0, 0, 0);
}

// Round 8
// 579.801 us; speedup vs baseline: 1.2400x; 1.0956x over previous
//
#include <hip/hip_runtime.h>
#include <hip/hip_bf16.h>
#include <math.h>

// B=64, N=512, D=1024, SHELL=64, RFF=32, ORDER=4, COMBINED=64
// R5: R4 + prologue issue-order fix. vmcnt(4) certifies "all but newest 4";
// the prologue must issue A(0)x4, B(0)x4, THEN B(1)x4 sequentially so the
// newest 4 at tile 0 are exactly B(1). (R4's interleaved prologue left
// A(0)g3/B(0)g3 uncertified -> tile-0 rows 192-255 race, absmax 0.77.)

using u16 = unsigned short;
typedef short short8 __attribute__((ext_vector_type(8)));   // 8 x bf16 (4 VGPR)
typedef float f32x4 __attribute__((ext_vector_type(4)));

__device__ __forceinline__ u16 f2bf(float f) {
  unsigned u = __float_as_uint(f);
  return (u16)((u + 0x7fffu + ((u >> 16) & 1u)) >> 16);   // RNE
}

// async global->LDS, 16B per lane; lds dest = wave-uniform base + lane*16
__device__ __forceinline__ void gload16(const u16* g, const u16* l) {
  __builtin_amdgcn_global_load_lds(
      (const __attribute__((address_space(1))) unsigned int*)(g),
      (__attribute__((address_space(3))) unsigned int*)(l),
      16, 0, 0);
}

// swizzled LDS read: row stride 128B, byte-in-row b XORed by (row&7)<<4
__device__ __forceinline__ short8 ldsrd(const u16* base, int row, int b) {
  int byte = row * 128 + (b ^ ((row & 7) << 4));
  return *reinterpret_cast<const short8*>(reinterpret_cast<const char*>(base) + byte);
}

// ---------------- x -> bf16 ----------------
__global__ __launch_bounds__(256) void convert_x_kernel(const float* __restrict__ in,
                                                        u16* __restrict__ out, int n4) {
  int idx = blockIdx.x * 256 + threadIdx.x;
  int stride = gridDim.x * 256;
  for (int i = idx; i < n4; i += stride) {
    float4 v = reinterpret_cast<const float4*>(in)[i];
    ushort4 o;
    o.x = f2bf(v.x); o.y = f2bf(v.y); o.z = f2bf(v.z); o.w = f2bf(v.w);
    reinterpret_cast<ushort4*>(out)[i] = o;
  }
}

// ---------------- weights -> bf16 ----------------
__global__ __launch_bounds__(256) void prep_weights_kernel(
    const float* __restrict__ Wv, const float* __restrict__ Wo,
    const float* __restrict__ Wsh, const float* __restrict__ Wch,
    const float* __restrict__ Wcb,
    u16* __restrict__ wvb, u16* __restrict__ wob,
    u16* __restrict__ wcat, u16* __restrict__ wcbb) {
  int i = blockIdx.x * 256 + threadIdx.x;
  if (i < 1048576) { wvb[i] = f2bf(Wv[i]); return; }
  i -= 1048576;
  if (i < 1048576) { wob[i] = f2bf(Wo[i]); return; }
  i -= 1048576;
  if (i < 131072) {  // Wcat: 128 rows x 1024 (rows 0-63 Wsh, row 64 Wch, rest 0)
    int row = i >> 10, e = i & 1023;
    float v = (row < 64) ? Wsh[i] : ((row == 64) ? Wch[e] : 0.0f);
    wcat[i] = f2bf(v);
    return;
  }
  i -= 131072;
  if (i < 40960) {   // Wcomb padded: 128 rows x 320
    int row = i / 320;
    wcbb[i] = f2bf(row < 64 ? Wcb[i] : 0.0f);
  }
}

// ================= gemm256: C = A @ Bt^T (+bias), 256x256 tile =================
// A: M x K (lda), Bt: N x K (ldb), K-contiguous. M%256==0, N%256==0, K%64==0, K>=192.
// OUT_MODE: 0 fp32 C[m*ldc+n], 1 bf16 C[m*ldc+n], 2 bf16 transposed C[n*ldc+m].
// Schedule per K-tile: vmcnt(4) -> certify BARRIER -> 4 phases of
// {ds_read || 2 gloads; bar; prio MFMA; bar}. Ledger: A(t+1)@P0-P1 (slot dead
// since t-1 P3), B(t+2)@P2-P3 (B regs cached at P0; all waves past P1 bar).
// Invariant: at tile t's vmcnt(4), the 4 newest in-flight loads are B(t+1).
template<int OUT_MODE>
__global__ __launch_bounds__(512, 2) void gemm256(
    const u16* __restrict__ A, const u16* __restrict__ Bt,
    const float* __restrict__ bias, void* __restrict__ Cv,
    int M, int N, int K, int lda, int ldb, int ldc,
    long long sA, long long sB, long long sC) {
  (void)M; (void)N;
  __shared__ u16 lds[65536];   // 128 KiB: buf c at c*32768 (A 16384 u16 | B 16384 u16)
  const int t = threadIdx.x;
  const int lane = t & 63;
  const int w = t >> 6;
  const u16* Ag = A + (size_t)blockIdx.z * sA;
  const u16* Bg = Bt + (size_t)blockIdx.z * sB;

  // XCD chunked swizzle on x-y plane (bijective when nwg%8==0)
  int gx = gridDim.x, gy = gridDim.y;
  int bid = blockIdx.y * gx + blockIdx.x;
  int nwg = gx * gy;
  if ((nwg & 7) == 0) { int cpx = nwg >> 3; bid = (bid & 7) * cpx + (bid >> 3); }
  const int m0 = (bid / gx) * 256;
  const int n0 = (bid % gx) * 256;

  const int wm = w >> 2;          // 2 wave-rows x 4 wave-cols; per-wave out 128x64
  const int wn = w & 3;
  const int rl = lane & 15;
  const int kq = lane >> 4;       // 16B chunk within 64B k-half

  // staging: gload group g covers rows g*64 + w*8 + (lane>>3); source col
  // pre-swizzled so linear LDS dest holds the XOR-swizzled layout.
  const int srow = w * 8 + (lane >> 3);
  const int scol = 8 * ((lane & 7) ^ ((lane >> 3) & 7));
  const u16* aS = Ag + (size_t)(m0 + srow) * lda + scol;
  const u16* bS = Bg + (size_t)(n0 + srow) * ldb + scol;

  const int NT = K >> 6;

  // prologue: SEQUENTIAL groups so vmcnt(4)'s newest-4 at tile 0 are B(1):
  // A(0)x4 -> buf0.A, then B(0)x4 -> buf0.B, then B(1)x4 -> buf1.B.
  #pragma unroll
  for (int g = 0; g < 4; ++g)
    gload16(aS + (size_t)(g * 64) * lda,      lds + w * 512 + g * 4096);
  #pragma unroll
  for (int g = 0; g < 4; ++g)
    gload16(bS + (size_t)(g * 64) * ldb,      lds + 16384 + w * 512 + g * 4096);
  #pragma unroll
  for (int g = 0; g < 4; ++g)
    gload16(bS + (size_t)(g * 64) * ldb + 64, lds + 32768 + 16384 + w * 512 + g * 4096);

  f32x4 acc[8][4] = {};

  for (int tt = 0; tt < NT; ++tt) {
    const int c = tt & 1, nc = c ^ 1;
    const u16* At  = lds + c * 32768;
    const u16* Btl = At + 16384;
    const u16* dstA = lds + nc * 32768 + w * 512;           // A(t+1)
    const u16* dstB = lds + c * 32768 + 16384 + w * 512;    // B(t+2)
    const int kA = (tt + 1 < NT) ? (tt + 1) << 6 : 0;       // clamp: dummy, unread
    const int kB = (tt + 2 < NT) ? (tt + 2) << 6 : 0;

    // own A(t),B(t) landed (B(t+1)'s 4 loads stay in flight) ...
    asm volatile("s_waitcnt vmcnt(4)" ::: "memory");
    // ... and collectively certified before ANY wave reads cross-staged rows.
    __builtin_amdgcn_s_barrier();
    __builtin_amdgcn_sched_barrier(0);

    short8 bq[4][2];
    #pragma unroll
    for (int p = 0; p < 4; ++p) {
      if (p == 0) {
        #pragma unroll
        for (int ni = 0; ni < 4; ++ni) {
          bq[ni][0] = ldsrd(Btl, wn * 64 + ni * 16 + rl, kq * 16);
          bq[ni][1] = ldsrd(Btl, wn * 64 + ni * 16 + rl, 64 + kq * 16);
        }
      }
      short8 a0k0 = ldsrd(At, wm * 128 + (2 * p + 0) * 16 + rl, kq * 16);
      short8 a0k1 = ldsrd(At, wm * 128 + (2 * p + 0) * 16 + rl, 64 + kq * 16);
      short8 a1k0 = ldsrd(At, wm * 128 + (2 * p + 1) * 16 + rl, kq * 16);
      short8 a1k1 = ldsrd(At, wm * 128 + (2 * p + 1) * 16 + rl, 64 + kq * 16);
      if (p < 2) {
        gload16(aS + (size_t)((2 * p + 0) * 64) * lda + kA, dstA + (2 * p + 0) * 4096);
        gload16(aS + (size_t)((2 * p + 1) * 64) * lda + kA, dstA + (2 * p + 1) * 4096);
      } else {
        gload16(bS + (size_t)((2 * (p - 2) + 0) * 64) * ldb + kB, dstB + (2 * (p - 2) + 0) * 4096);
        gload16(bS + (size_t)((2 * (p - 2) + 1) * 64) * ldb + kB, dstB + (2 * (p - 2) + 1) * 4096);
      }
      __builtin_amdgcn_s_barrier();
      __builtin_amdgcn_s_setprio(1);
      #pragma unroll
      for (int ni = 0; ni < 4; ++ni) {
        acc[2 * p][ni]     = __builtin_amdgcn_mfma_f32_16x16x32_bf16(a0k0, bq[ni][0], acc[2 * p][ni], 0, 0, 0);
        acc[2 * p][ni]     = __builtin_amdgcn_mfma_f32_16x16x32_bf16(a0k1, bq[ni][1], acc[2 * p][ni], 0, 0, 0);
        acc[2 * p + 1][ni] = __builtin_amdgcn_mfma_f32_16x16x32_bf16(a1k0, bq[ni][0], acc[2 * p + 1][ni], 0, 0, 0);
        acc[2 * p + 1][ni] = __builtin_amdgcn_mfma_f32_16x16x32_bf16(a1k1, bq[ni][1], acc[2 * p + 1][ni], 0, 0, 0);
      }
      __builtin_amdgcn_s_setprio(0);
      __builtin_amdgcn_s_barrier();
    }
  }

  // drain tail dummy prefetches before LDS reuse / epilogue
  asm volatile("s_waitcnt vmcnt(0)" ::: "memory");

  // C/D layout: col = lane&15, row = (lane>>4)*4 + reg
  const int cm = (lane >> 4) * 4;
  #pragma unroll
  for (int mi = 0; mi < 8; ++mi) {
    #pragma unroll
    for (int ni = 0; ni < 4; ++ni) {
      const int gm = m0 + wm * 128 + mi * 16 + cm;
      const int gn = n0 + wn * 64 + ni * 16 + rl;
      const float bsv = bias ? bias[gn] : 0.0f;
      if (OUT_MODE == 0) {
        float* C = (float*)Cv + (size_t)blockIdx.z * sC;
        #pragma unroll
        for (int r = 0; r < 4; ++r)
          C[(size_t)(gm + r) * ldc + gn] = acc[mi][ni][r] + bsv;
      } else if (OUT_MODE == 1) {
        u16* C = (u16*)Cv + (size_t)blockIdx.z * sC;
        #pragma unroll
        for (int r = 0; r < 4; ++r)
          C[(size_t)(gm + r) * ldc + gn] = f2bf(acc[mi][ni][r] + bsv);
      } else {
        u16* C = (u16*)Cv + (size_t)blockIdx.z * sC;
        ushort4 pk;
        pk.x = f2bf(acc[mi][ni][0] + bsv);
        pk.y = f2bf(acc[mi][ni][1] + bsv);
        pk.z = f2bf(acc[mi][ni][2] + bsv);
        pk.w = f2bf(acc[mi][ni][3] + bsv);
        *reinterpret_cast<ushort4*>(&C[(size_t)gn * ldc + gm]) = pk;
      }
    }
  }
}

// ---------------- 128-tile GEMM (small shapes: SC, phi) ----------------
template<int OUT_MODE>
__global__ __launch_bounds__(256) void gemm_bt(
    const u16* __restrict__ A, const u16* __restrict__ Bt,
    const float* __restrict__ bias, void* __restrict__ Cv,
    int M, int N, int K, int lda, int ldb, int ldc,
    long long sA, long long sB, long long sC) {
  (void)M; (void)N;
  __shared__ u16 lA[128 * 32];
  __shared__ u16 lB[128 * 32];
  const int t = threadIdx.x;
  const int lane = t & 63;
  const int w = t >> 6;
  const u16* Ag = A + (size_t)blockIdx.z * sA;
  const u16* Bg = Bt + (size_t)blockIdx.z * sB;

  int gx = gridDim.x, gy = gridDim.y;
  int bid = blockIdx.y * gx + blockIdx.x;
  int nwg = gx * gy;
  if ((nwg & 7) == 0) { int cpx = nwg >> 3; bid = (bid & 7) * cpx + (bid >> 3); }
  const int m0 = (bid / gx) * 128;
  const int n0 = (bid % gx) * 128;

  const int wm = (w >> 1) * 64;
  const int wn = (w & 1) * 64;
  const int rl = lane & 15;
  const int kl = (lane >> 4) * 8;
  const int rs = w * 32 + (lane >> 2);
  const int cs = (lane & 3) * 8;
  u16* ldsA = &lA[w * 1024];
  u16* ldsB = &lB[w * 1024];

  f32x4 acc[4][4] = {};

  for (int k0 = 0; k0 < K; k0 += 32) {
    const u16* ga = Ag + (size_t)(m0 + rs) * lda + k0 + cs;
    const u16* gb = Bg + (size_t)(n0 + rs) * ldb + k0 + cs;
    gload16(ga,                    ldsA);
    gload16(ga + (size_t)16 * lda, ldsA + 512);
    gload16(gb,                    ldsB);
    gload16(gb + (size_t)16 * ldb, ldsB + 512);
    __syncthreads();
    short8 af[4], bfr[4];
    #pragma unroll
    for (int mi = 0; mi < 4; ++mi)
      af[mi] = *reinterpret_cast<const short8*>(&lA[(wm + mi * 16 + rl) * 32 + kl]);
    #pragma unroll
    for (int ni = 0; ni < 4; ++ni)
      bfr[ni] = *reinterpret_cast<const short8*>(&lB[(wn + ni * 16 + rl) * 32 + kl]);
    #pragma unroll
    for (int mi = 0; mi < 4; ++mi) {
      #pragma unroll
      for (int ni = 0; ni < 4; ++ni)
        acc[mi][ni] = __builtin_amdgcn_mfma_f32_16x16x32_bf16(af[mi], bfr[ni], acc[mi][ni], 0, 0, 0);
    }
    __syncthreads();
  }

  const int cm = (lane >> 4) * 4;
  #pragma unroll
  for (int mi = 0; mi < 4; ++mi) {
    #pragma unroll
    for (int ni = 0; ni < 4; ++ni) {
      const int gm = m0 + wm + mi * 16 + cm;
      const int gn = n0 + wn + ni * 16 + rl;
      const float bsv = bias ? bias[gn] : 0.0f;
      if (OUT_MODE == 0) {
        float* C = (float*)Cv + (size_t)blockIdx.z * sC;
        #pragma unroll
        for (int r = 0; r < 4; ++r)
          C[(size_t)(gm + r) * ldc + gn] = acc[mi][ni][r] + bsv;
      } else {
        u16* C = (u16*)Cv + (size_t)blockIdx.z * sC;
        #pragma unroll
        for (int r = 0; r < 4; ++r)
          C[(size_t)(gm + r) * ldc + gn] = f2bf(acc[mi][ni][r] + bsv);
      }
    }
  }
}

// ---------------- features: SC(fp32 32768x128) -> tp(bf16 32768x320) ----------------
__global__ __launch_bounds__(256) void features_kernel(
    const float* __restrict__ SC, const float* __restrict__ b_shell,
    const float* __restrict__ b_charge, const float* __restrict__ omega,
    const float* __restrict__ rff_bias, u16* __restrict__ tp) {
  __shared__ __align__(16) float sm[4][64];
  const int lane = threadIdx.x & 63;
  const int w = threadIdx.x >> 6;
  const int row = blockIdx.x * 4 + w;
  const float* sc = SC + (size_t)row * 128;
  float s = sc[lane] + b_shell[lane];
  float ss = s * s;
  #pragma unroll
  for (int off = 32; off > 0; off >>= 1) ss += __shfl_xor(ss, off);
  float shell = s / fmaxf(sqrtf(ss), 1e-12f);
  sm[w][lane] = shell;
  const float q = tanhf(sc[64] + b_charge[0]);
  __syncthreads();
  const int r = lane & 31;
  float p = rff_bias[r];
  const float4* om = reinterpret_cast<const float4*>(omega + r * 64);
  const float4* sv = reinterpret_cast<const float4*>(sm[w]);
  #pragma unroll
  for (int d = 0; d < 16; ++d) {
    float4 o4 = om[d], s4 = sv[d];
    p += o4.x * s4.x + o4.y * s4.y + o4.z * s4.z + o4.w * s4.w;
  }
  const float RFFS = 0.13767388f;  // sqrt(2/64)*sqrt(exp(-0.5))
  float phis = (lane < 32) ? cosf(p) * RFFS : sinf(p) * RFFS;
  float q2 = q * q;
  float pc[5];
  pc[0] = 1.0f;
  pc[1] = q;
  pc[2] = 0.70710678f * q2;
  pc[3] = 0.40824829f * q2 * q;
  pc[4] = 0.20412415f * q2 * q2;
  u16* o = tp + (size_t)row * 320 + lane;
  #pragma unroll
  for (int m = 0; m < 5; ++m) o[m * 64] = f2bf(pc[m] * phis);
}

// ======== fused QK^T + Toeplitz + causal softmax -> attn (bf16) ========
// block: 256 thr (4 waves), computes 64 Q-rows x 512 keys for one batch.
// phi: 32768 x 128 bf16 (cols 0-63 valid). grid (8 row-tiles, 64 batches).
__global__ __launch_bounds__(256, 2) void qk_softmax_kernel(
    const u16* __restrict__ phi, const float* __restrict__ log_temp,
    u16* __restrict__ attn) {
  __shared__ u16 sm[36864];    // K: 512x64 (32768 u16) | Q: 64x64 (4096 u16)
  const int t = threadIdx.x;
  const int lane = t & 63;
  const int w = t >> 6;
  const int b = blockIdx.y;
  const int rt = blockIdx.x;
  const u16* phiB = phi + (size_t)b * 512 * 128;

  const int srow = w * 8 + (lane >> 3);
  const int scol = 8 * ((lane & 7) ^ ((lane >> 3) & 7));
  // stage K: 16 rounds of 32 rows
  #pragma unroll
  for (int rnd = 0; rnd < 16; ++rnd)
    gload16(phiB + (size_t)(rnd * 32 + srow) * 128 + scol, sm + rnd * 2048 + w * 512);
  // stage Q: 2 rounds
  #pragma unroll
  for (int rnd = 0; rnd < 2; ++rnd)
    gload16(phiB + (size_t)(rt * 64 + rnd * 32 + srow) * 128 + scol,
            sm + 32768 + rnd * 2048 + w * 512);
  __syncthreads();   // drains vmcnt

  const u16* Kb = sm;
  const u16* Qb = sm + 32768;
  const int rl = lane & 15;
  const int kq = lane >> 4;

  short8 af0 = ldsrd(Qb, w * 16 + rl, kq * 16);
  short8 af1 = ldsrd(Qb, w * 16 + rl, 64 + kq * 16);
  f32x4 acc[32] = {};
  #pragma unroll
  for (int cf = 0; cf < 32; ++cf) {
    short8 b0 = ldsrd(Kb, cf * 16 + rl, kq * 16);
    short8 b1 = ldsrd(Kb, cf * 16 + rl, 64 + kq * 16);
    acc[cf] = __builtin_amdgcn_mfma_f32_16x16x32_bf16(af0, b0, acc[cf], 0, 0, 0);
    acc[cf] = __builtin_amdgcn_mfma_f32_16x16x32_bf16(af1, b1, acc[cf], 0, 0, 0);
  }

  const float invt = 1.0f / (log1pf(expf(log_temp[0])) + 0.1f);
  // col factors e^{0.03 j}, j = cf*16 + rl
  float tj[32];
  #pragma unroll
  for (int cf = 0; cf < 32; ++cf) tj[cf] = expf(0.03f * (float)(cf * 16 + rl));

  u16* Ar = attn + ((size_t)b * 512 + rt * 64 + w * 16 + (lane >> 4) * 4) * 512 + rl;
  #pragma unroll
  for (int r = 0; r < 4; ++r) {
    const int i = rt * 64 + w * 16 + (lane >> 4) * 4 + r;
    const float ti = expf(-0.03f * (float)i) * invt;
    float z[32];
    #pragma unroll
    for (int cf = 0; cf < 32; ++cf) {
      const int j = cf * 16 + rl;
      z[cf] = (j <= i) ? acc[cf][r] * tj[cf] * ti : -INFINITY;
    }
    float m = z[0];
    #pragma unroll
    for (int cf = 1; cf < 32; ++cf) m = fmaxf(m, z[cf]);
    #pragma unroll
    for (int off = 8; off > 0; off >>= 1) m = fmaxf(m, __shfl_xor(m, off));
    float sum = 0.0f;
    #pragma unroll
    for (int cf = 0; cf < 32; ++cf) { z[cf] = expf(z[cf] - m); sum += z[cf]; }
    #pragma unroll
    for (int off = 8; off > 0; off >>= 1) sum += __shfl_xor(sum, off);
    const float rinv = 1.0f / sum;
    #pragma unroll
    for (int cf = 0; cf < 32; ++cf)
      Ar[(size_t)r * 512 + cf * 16] = f2bf(z[cf] * rinv);
  }
}

extern "C" void kernel_launch(void* const* d_in, const int* in_sizes, int n_in,
                              void* d_out, int out_size, void* d_ws, size_t ws_size,
                              hipStream_t stream) {
  (void)in_sizes; (void)n_in; (void)out_size; (void)ws_size;
  const float* x     = (const float*)d_in[0];
  const float* Wch   = (const float*)d_in[1];
  const float* bch   = (const float*)d_in[2];
  const float* Wsh   = (const float*)d_in[3];
  const float* bsh   = (const float*)d_in[4];
  const float* omega = (const float*)d_in[5];
  const float* rffb  = (const float*)d_in[6];
  const float* Wcb   = (const float*)d_in[7];
  const float* Wv    = (const float*)d_in[8];
  const float* bv    = (const float*)d_in[9];
  const float* Wo    = (const float*)d_in[10];
  const float* bo    = (const float*)d_in[11];
  const float* lt    = (const float*)d_in[12];
  float* out = (float*)d_out;
  char* ws = (char*)d_ws;

  // ws layout (aliased; ~181 MB total)
  u16*   xb   = (u16*)(ws + 0);            // later reused as out2
  u16*   vt   = (u16*)(ws + 67108864);     // early reused as SC (fp32)
  float* sc   = (float*)(ws + 67108864);   // dead before vt written
  u16*   attn = (u16*)(ws + 134217728);    // early reused as tp
  u16*   tp   = (u16*)(ws + 134217728);    // dead before attn written
  u16*   phi  = (u16*)(ws + 167772160);    // 32768 x 128 bf16
  u16*   wvb  = (u16*)(ws + 176160768);
  u16*   wob  = (u16*)(ws + 178257920);
  u16*   wcat = (u16*)(ws + 180355072);    // 128 x 1024
  u16*   wcbb = (u16*)(ws + 180617216);    // 128 x 320
  u16*   out2 = xb;

  convert_x_kernel<<<8192, 256, 0, stream>>>(x, xb, 33554432 / 4);
  prep_weights_kernel<<<8864, 256, 0, stream>>>(Wv, Wo, Wsh, Wch, Wcb, wvb, wob, wcat, wcbb);
  // SC = x @ [Wsh;Wch]^T  (fp32 out)
  gemm_bt<0><<<dim3(1, 256, 1), 256, 0, stream>>>(xb, wcat, nullptr, sc,
      32768, 128, 1024, 1024, 1024, 128, 0, 0, 0);
  features_kernel<<<8192, 256, 0, stream>>>(sc, bsh, bch, omega, rffb, tp);
  // phi = tp @ Wcomb^T (bf16 out, 128 cols, first 64 valid, rest zero)
  gemm_bt<1><<<dim3(1, 256, 1), 256, 0, stream>>>(tp, wcbb, nullptr, phi,
      32768, 128, 320, 320, 320, 128, 0, 0, 0);
  // fused logits + Toeplitz + causal softmax -> attn (bf16)
  qk_softmax_kernel<<<dim3(8, 64), 256, 0, stream>>>(phi, lt, attn);
  // Vt[d][tok] = (x @ Wv^T + bv)^T  (bf16 transposed epilogue)
  gemm256<2><<<dim3(4, 128, 1), 512, 0, stream>>>(xb, wvb, bv, vt,
      32768, 1024, 1024, 1024, 1024, 32768, 0, 0, 0);
  // out2[b] = attn_b @ V_b  (Bt = Vt + b*512, ldb = 32768)
  gemm256<1><<<dim3(4, 2, 64), 512, 0, stream>>>(attn, vt, nullptr, out2,
      512, 1024, 512, 512, 32768, 1024, 262144, 512, 524288);
  // out = out2 @ Wo^T + bo  (fp32 into d_out)
  gemm256<0><<<dim3(4, 128, 1), 512, 0, stream>>>(out2, wob, bo, out,
      32768, 1024, 1024, 1024, 1024, 1024, 0, 0, 0);
}